// Round 5
// baseline (9400.504 us; speedup 1.0000x reference)
//
#include <hip/hip_runtime.h>
#include <cstdint>
#include <cstddef>

#define SS   512
#define BB   64
#define EMBD 768
#define HIDN 512
#define G4   2048
#define NTAG 9

typedef __attribute__((ext_vector_type(8))) __bf16 bf16x8;
typedef __attribute__((ext_vector_type(4))) float  f32x4;
typedef unsigned long long u64;

union HCast { f32x4 f; bf16x8 h; };
union UCast { f32x4 f; unsigned u[4]; };

// ---- device-scope (MALL coherence-point) bypass ops: sc0 sc1 ---------------
// (exact ops proven in R0/R2 across hundreds of replays)
__device__ inline void load_h16_mall(const void* base, f32x4* f) {
  asm volatile(
    "global_load_dwordx4 %0, %16, off sc0 sc1\n\t"
    "global_load_dwordx4 %1, %16, off offset:64 sc0 sc1\n\t"
    "global_load_dwordx4 %2, %16, off offset:128 sc0 sc1\n\t"
    "global_load_dwordx4 %3, %16, off offset:192 sc0 sc1\n\t"
    "global_load_dwordx4 %4, %16, off offset:256 sc0 sc1\n\t"
    "global_load_dwordx4 %5, %16, off offset:320 sc0 sc1\n\t"
    "global_load_dwordx4 %6, %16, off offset:384 sc0 sc1\n\t"
    "global_load_dwordx4 %7, %16, off offset:448 sc0 sc1\n\t"
    "global_load_dwordx4 %8, %16, off offset:512 sc0 sc1\n\t"
    "global_load_dwordx4 %9, %16, off offset:576 sc0 sc1\n\t"
    "global_load_dwordx4 %10, %16, off offset:640 sc0 sc1\n\t"
    "global_load_dwordx4 %11, %16, off offset:704 sc0 sc1\n\t"
    "global_load_dwordx4 %12, %16, off offset:768 sc0 sc1\n\t"
    "global_load_dwordx4 %13, %16, off offset:832 sc0 sc1\n\t"
    "global_load_dwordx4 %14, %16, off offset:896 sc0 sc1\n\t"
    "global_load_dwordx4 %15, %16, off offset:960 sc0 sc1\n\t"
    "s_waitcnt vmcnt(0)"
    : "=&v"(f[0]), "=&v"(f[1]), "=&v"(f[2]), "=&v"(f[3]),
      "=&v"(f[4]), "=&v"(f[5]), "=&v"(f[6]), "=&v"(f[7]),
      "=&v"(f[8]), "=&v"(f[9]), "=&v"(f[10]), "=&v"(f[11]),
      "=&v"(f[12]), "=&v"(f[13]), "=&v"(f[14]), "=&v"(f[15])
    : "v"(base)
    : "memory");
}
__device__ inline void store_h8_mall(void* p, u64 v) {
  asm volatile("global_store_dwordx2 %0, %1, off sc0 sc1" :: "v"(p), "v"(v) : "memory");
}
__device__ inline void store_i32_bypass(int* p, int v) {
  asm volatile("global_store_dword %0, %1, off sc0 sc1" :: "v"(p), "v"(v) : "memory");
}
__device__ inline int load_i32_bypass(const int* p) {
  int v;
  asm volatile("global_load_dword %0, %1, off sc0 sc1\n\ts_waitcnt vmcnt(0)"
               : "=v"(v) : "v"(p) : "memory");
  return v;
}

// ---------------------------------------------------------------------------
// fp32 -> bf16 converter
// ---------------------------------------------------------------------------
__global__ __launch_bounds__(256) void cvt_kernel(
    const float* __restrict__ src, __bf16* __restrict__ dst, int n8)
{
  int i = blockIdx.x * 256 + threadIdx.x;
  if (i >= n8) return;
  f32x4 a = *reinterpret_cast<const f32x4*>(src + 8 * (size_t)i);
  f32x4 b = *reinterpret_cast<const f32x4*>(src + 8 * (size_t)i + 4);
  bf16x8 o;
  o[0]=(__bf16)a[0]; o[1]=(__bf16)a[1]; o[2]=(__bf16)a[2]; o[3]=(__bf16)a[3];
  o[4]=(__bf16)b[0]; o[5]=(__bf16)b[1]; o[6]=(__bf16)b[2]; o[7]=(__bf16)b[3];
  *reinterpret_cast<bf16x8*>(dst + 8 * (size_t)i) = o;
}

// ---------------------------------------------------------------------------
// Input projection, bf16 MFMA (unchanged, verified).
// ---------------------------------------------------------------------------
__global__ __launch_bounds__(256, 2) void proj_kernel(
    const __bf16* __restrict__ xb, const __bf16* __restrict__ wfb,
    const __bf16* __restrict__ wbb, const float* __restrict__ bias_f,
    const float* __restrict__ bias_b, float* __restrict__ xp,
    int t0, int chunk)
{
  const int nb = blockIdx.x;
  const int tt = blockIdx.y;
  const int d  = blockIdx.z;
  const int s  = d ? (SS - 1 - (t0 + tt)) : (t0 + tt);
  const __bf16* __restrict__ wih = d ? wbb : wfb;
  const float*  __restrict__ bias = d ? bias_b : bias_f;

  const int t = threadIdx.x, wv = t >> 6, l = t & 63;
  const int quad = l >> 4, col = l & 15;

  const __bf16* brow[8];
  float bj[8];
  const int pbase = 128 * nb;
#pragma unroll
  for (int j = 0; j < 8; j++) {
    int p    = pbase + 16 * j + col;
    int gate = p & 3;
    int hc   = 16 * (p >> 6) + 4 * ((p >> 2) & 3) + ((p >> 4) & 3);
    int g    = gate * HIDN + hc;
    brow[j]  = wih + (size_t)g * EMBD + 8 * quad;
    bj[j]    = bias[g];
  }
  const __bf16* arow = xb + ((size_t)(16 * wv + col) * SS + s) * EMBD + 8 * quad;

  f32x4 acc[8];
#pragma unroll
  for (int j = 0; j < 8; j++) acc[j] = f32x4{0.f, 0.f, 0.f, 0.f};

  for (int kk = 0; kk < 24; kk++) {
    bf16x8 a = *reinterpret_cast<const bf16x8*>(arow + 32 * kk);
#pragma unroll
    for (int j = 0; j < 8; j++) {
      bf16x8 b = *reinterpret_cast<const bf16x8*>(brow[j] + 32 * kk);
      acc[j] = __builtin_amdgcn_mfma_f32_16x16x32_bf16(a, b, acc[j], 0, 0, 0);
    }
  }
  float* xpd = xp + (size_t)(d * chunk + tt) * (size_t)G4 * BB + 16 * wv + 4 * quad;
#pragma unroll
  for (int j = 0; j < 8; j++) {
    int p = pbase + 16 * j + col;
    f32x4 v = acc[j];
    v[0] += bj[j]; v[1] += bj[j]; v[2] += bj[j]; v[3] += bj[j];
    *reinterpret_cast<f32x4*>(xpd + (size_t)p * BB) = v;
  }
}

// ---------------------------------------------------------------------------
// Recurrence: 32 WGs x 512 thr (8 waves, 1 WG/CU). Waves 0-3 ("set 0") poll
// the full h matrix (proven sc0sc1 dataflow sentinel) and publish it to a
// 64 KB XOR-swizzled LDS buffer; waves 4-7 ("set 1") read fragments from LDS
// and compute a second 64-col gate slice. This halves MALL poll traffic
// (4 MB -> 2 MB per step) and halves the number of polling waves, and set-1
// compute overlaps set-0's next poll. Cross-WG sync stays pure dataflow
// (bf16 NaN sentinel 0xFFFF, impossible for real h since |h|<=1).
// ---------------------------------------------------------------------------
struct RecCtl {
  int prog[2][64];
  int pad[128];
};

struct RecParams {
  const float* xp;       // [d][chunk][2048 packed][64] fp32
  const float* whh_f;    // [2048][512] fp32
  const float* whh_b;
  __bf16* hh;            // [d][chunk+1][64][512] bf16
  float*  cT;            // [d][512][64] fp32
  RecCtl* ctl;
  int     chunk;
};

__global__ __launch_bounds__(512, 2) void rec_kernel(RecParams p)
{
  const int wg   = blockIdx.x;     // 0..31
  const int d    = wg >> 4;        // direction
  const int slw  = wg & 15;        // WG within direction
  const int t    = threadIdx.x;    // 0..511
  const int w    = t >> 6;         // wave 0..7
  const int ws2  = w >> 2;         // col-set: 0 = poller, 1 = LDS consumer
  const int wv   = w & 3;          // batch quad
  const int l    = t & 63;
  const int quad = l >> 4;
  const int col  = l & 15;
  const int hcl  = col >> 2;
  const int gate = col & 3;
  const int j4   = col & 3;
  const int g    = 2 * slw + ws2;  // 64-col group 0..31 (old 'sl')

  const size_t slotsz = (size_t)BB * HIDN;

  // 64 KB LDS h-mirror; 16B units, kk XOR-swizzled by row to avoid bank camp
  __shared__ f32x4 hlds[256 * 16];

  // ---- prologue: sentinel-fill slots 1..chunk (both dirs), bypass stores ---
  {
    const size_t qper = (size_t)p.chunk * slotsz / 4;   // 8B qwords per dir
    const size_t totq = 2 * qper;
    const size_t gtid = (size_t)wg * 512 + t;
    for (size_t q = gtid; q < totq; q += (size_t)32 * 512) {
      const size_t dd  = q / qper;
      const size_t off = q - dd * qper;
      char* dst = (char*)p.hh + (dd * (p.chunk + 1) + 1) * slotsz * 2 + off * 8;
      store_h8_mall(dst, 0xFFFFFFFFFFFFFFFFull);
    }
    __builtin_amdgcn_s_waitcnt(0);
    __syncthreads();
    if (t == 0) store_i32_bypass(&p.ctl->prog[0][wg], 1);
    if (w == 0) {
      const int* slot = &p.ctl->prog[0][l];
      while (true) {
        int v = (l < 32) ? load_i32_bypass(slot) : 1;
        if (__ballot(v != 0) == ~0ull) break;
        __builtin_amdgcn_s_sleep(1);
      }
    }
    __syncthreads();
  }

  const float* __restrict__ whh = d ? p.whh_b : p.whh_f;

  bf16x8 bfrag[4][16];
#pragma unroll
  for (int j = 0; j < 4; j++) {
    const int hcb = 16 * g + 4 * hcl + j;
    const float* wr = whh + (size_t)(gate * HIDN + hcb) * HIDN + 8 * quad;
#pragma unroll
    for (int kk = 0; kk < 16; kk++) {
      f32x4 w0 = *reinterpret_cast<const f32x4*>(wr + 32 * kk);
      f32x4 w1 = *reinterpret_cast<const f32x4*>(wr + 32 * kk + 4);
      bf16x8 v;
      v[0] = (__bf16)w0[0]; v[1] = (__bf16)w0[1]; v[2] = (__bf16)w0[2]; v[3] = (__bf16)w0[3];
      v[4] = (__bf16)w1[0]; v[5] = (__bf16)w1[1]; v[6] = (__bf16)w1[2]; v[7] = (__bf16)w1[3];
      bfrag[j][kk] = v;
    }
  }

  const int bA = 16 * wv + col;
  const int bC = 16 * wv + 4 * quad + gate;
  const int hcs = 16 * g + 4 * hcl;
  const int rowp = bA * 4 + quad;          // 0..255, LDS row
  __bf16* hhd = p.hh + (size_t)d * (p.chunk + 1) * slotsz;
  const float* xpd = p.xp + (size_t)d * p.chunk * ((size_t)G4 * BB);

  float c[4];
#pragma unroll
  for (int j = 0; j < 4; j++)
    c[j] = p.cT[((size_t)d * HIDN + hcs + j) * BB + bC];

  f32x4 xpn[4];
#pragma unroll
  for (int j = 0; j < 4; j++)
    xpn[j] = *reinterpret_cast<const f32x4*>(
        xpd + (size_t)(64 * g + 16 * j + col) * BB + 16 * wv + 4 * quad);

  u64 hword = 0;
  for (int tt = 0; tt < p.chunk; tt++) {
    f32x4 araw[16];
    if (ws2 == 0) {
      // --- dataflow poll (proven MALL path), then publish to LDS ---
      const char* hbase = (const char*)hhd + (size_t)tt * slotsz * 2
                        + (size_t)bA * (HIDN * 2) + quad * 16;
      for (;;) {
        load_h16_mall(hbase, araw);
        unsigned mx = 0u;
#pragma unroll
        for (int kk = 0; kk < 16; kk++) {
          UCast q; q.f = araw[kk];
          unsigned a01 = q.u[0] > q.u[1] ? q.u[0] : q.u[1];
          unsigned a23 = q.u[2] > q.u[3] ? q.u[2] : q.u[3];
          unsigned am  = a01 > a23 ? a01 : a23;
          mx = mx > am ? mx : am;
        }
        if (__all(mx != 0xFFFFFFFFu)) break;
        __builtin_amdgcn_s_sleep(1);
      }
#pragma unroll
      for (int kk = 0; kk < 16; kk++)
        hlds[rowp * 16 + (kk ^ (rowp & 15))] = araw[kk];
    }
    __syncthreads();                       // h published
    if (ws2 == 1) {
#pragma unroll
      for (int kk = 0; kk < 16; kk++)
        araw[kk] = hlds[rowp * 16 + (kk ^ (rowp & 15))];
    }
    __syncthreads();                       // consume complete; set-0 may reuse LDS next step

    bf16x8 afrag[16];
#pragma unroll
    for (int kk = 0; kk < 16; kk++) { HCast hc_; hc_.f = araw[kk]; afrag[kk] = hc_.h; }

    f32x4 acc[4][2];
#pragma unroll
    for (int j = 0; j < 4; j++) {
      acc[j][0] = xpn[j];
      acc[j][1] = f32x4{0.f, 0.f, 0.f, 0.f};
    }
#pragma unroll
    for (int kk = 0; kk < 16; kk += 2) {
#pragma unroll
      for (int j = 0; j < 4; j++) {
        acc[j][0] = __builtin_amdgcn_mfma_f32_16x16x32_bf16(afrag[kk],     bfrag[j][kk],     acc[j][0], 0, 0, 0);
        acc[j][1] = __builtin_amdgcn_mfma_f32_16x16x32_bf16(afrag[kk + 1], bfrag[j][kk + 1], acc[j][1], 0, 0, 0);
      }
    }

    hword = 0;
#pragma unroll
    for (int j = 0; j < 4; j++) {
      float v0 = acc[j][0][0] + acc[j][1][0];
      float v1 = acc[j][0][1] + acc[j][1][1];
      float v2 = acc[j][0][2] + acc[j][1][2];
      float v3 = acc[j][0][3] + acc[j][1][3];
      {
        float t0 = __shfl_xor(v1, 1); float t1 = __shfl_xor(v0, 1);
        float t2 = __shfl_xor(v3, 1); float t3 = __shfl_xor(v2, 1);
        if (j4 & 1) { v0 = t0; v2 = t2; } else { v1 = t1; v3 = t3; }
        float u0 = __shfl_xor(v2, 2); float u1 = __shfl_xor(v3, 2);
        float u2 = __shfl_xor(v0, 2); float u3 = __shfl_xor(v1, 2);
        if (j4 & 2) { v0 = u0; v1 = u1; } else { v2 = u2; v3 = u3; }
      }
      float ig = 1.f / (1.f + __expf(-v0));
      float fg = 1.f / (1.f + __expf(-v1));
      float gg = 1.f - 2.f / (__expf(2.f * v2) + 1.f);
      float og = 1.f / (1.f + __expf(-v3));
      c[j] = fg * c[j] + ig * gg;
      float hn = og * (1.f - 2.f / (__expf(2.f * c[j]) + 1.f));
      union { __bf16 b; unsigned short u; } cv; cv.b = (__bf16)hn;
      hword |= (u64)cv.u << (16 * j);
    }
    store_h8_mall((char*)hhd + (size_t)(tt + 1) * slotsz * 2
                  + (size_t)bC * (HIDN * 2) + (size_t)hcs * 2, hword);

    if (tt + 1 < p.chunk) {
#pragma unroll
      for (int j = 0; j < 4; j++)
        xpn[j] = *reinterpret_cast<const f32x4*>(
            xpd + (size_t)(tt + 1) * ((size_t)G4 * BB)
            + (size_t)(64 * g + 16 * j + col) * BB + 16 * wv + 4 * quad);
    }
  }

  // chunk==1 safety: carry store to slot 0 could race a WG still at tt=0.
  if (p.chunk == 1) {
    __builtin_amdgcn_s_waitcnt(0);
    __syncthreads();
    if (t == 0) store_i32_bypass(&p.ctl->prog[1][wg], 1);
    if (w == 0) {
      const int* slot = &p.ctl->prog[1][l];
      while (true) {
        int v = (l < 32) ? load_i32_bypass(slot) : 1;
        if (__ballot(v != 0) == ~0ull) break;
        __builtin_amdgcn_s_sleep(1);
      }
    }
    __syncthreads();
  }

  store_h8_mall((char*)hhd + (size_t)bC * (HIDN * 2) + (size_t)hcs * 2, hword);
#pragma unroll
  for (int j = 0; j < 4; j++)
    p.cT[((size_t)d * HIDN + hcs + j) * BB + bC] = c[j];
  __builtin_amdgcn_s_waitcnt(0);
}

// ---------------------------------------------------------------------------
__global__ __launch_bounds__(256) void emis_kernel(
    const __bf16* __restrict__ hh, const float* __restrict__ w_out,
    float* __restrict__ emis_f, float* __restrict__ emis_b,
    int t0, int chunk)
{
  const int tt = blockIdx.x;
  const int d  = blockIdx.y;
  const int t  = threadIdx.x;
  const int b  = t & 63;
  const int grp = t >> 6;

  const __bf16* hp = hh + ((size_t)d * (chunk + 1) + tt + 1) * ((size_t)BB * HIDN)
                   + (size_t)b * HIDN;
  const float* w0 = w_out + (size_t)grp * (2 * HIDN) + d * HIDN;
  const float* w1 = w_out + (size_t)(grp + 4) * (2 * HIDN) + d * HIDN;
  const float* w2 = w_out + (size_t)8 * (2 * HIDN) + d * HIDN;

  float a0 = 0.f, a1 = 0.f, a2 = 0.f;
  for (int k = 0; k < HIDN; k += 8) {
    bf16x8 hv8 = *reinterpret_cast<const bf16x8*>(hp + k);
#pragma unroll
    for (int j = 0; j < 8; j++) {
      float hv = (float)hv8[j];
      a0 += hv * w0[k + j];
      a1 += hv * w1[k + j];
      a2 += hv * w2[k + j];
    }
  }
  const int sidx = (d == 0) ? (t0 + tt) : (SS - 1 - (t0 + tt));
  float* dst = d ? emis_b : emis_f;
  dst[((size_t)sidx * BB + b) * NTAG + grp]     = a0;
  dst[((size_t)sidx * BB + b) * NTAG + grp + 4] = a1;
  if (grp == 0) dst[((size_t)sidx * BB + b) * NTAG + 8] = a2;
}

// ---------------------------------------------------------------------------
__global__ __launch_bounds__(64) void crf_kernel(
    const float* __restrict__ emis_f, const float* __restrict__ emis_b,
    const float* __restrict__ b_out, const float* __restrict__ start_tr,
    const float* __restrict__ end_tr, const float* __restrict__ trans,
    const int* __restrict__ mask, const int* __restrict__ target,
    float* __restrict__ llh)
{
  const int b    = blockIdx.x;
  const int lane = threadIdx.x;

  auto E = [&](int s, int tg) -> float {
    size_t o = ((size_t)s * BB + b) * NTAG + tg;
    return emis_f[o] + emis_b[o] + b_out[tg];
  };

  float numpart = 0.f;
  int msum = 0;
  for (int s = lane; s < SS; s += 64) {
    int m = mask[b * SS + s];
    msum += m;
    if (s >= 1 && m > 0) {
      int tp = target[b * SS + s - 1];
      int tc = target[b * SS + s];
      numpart += trans[tp * NTAG + tc] + E(s, tc);
    }
  }
#pragma unroll
  for (int off = 32; off > 0; off >>= 1) {
    numpart += __shfl_down(numpart, off, 64);
    msum    += __shfl_down(msum, off, 64);
  }

  const int tc = lane;
  const bool act = (tc < NTAG);
  float trc[NTAG] = {0.f};
  float alpha = 0.f;
  if (act) {
#pragma unroll
    for (int i = 0; i < NTAG; i++) trc[i] = trans[i * NTAG + tc];
    alpha = start_tr[tc] + E(0, tc);
  }
  for (int s = 1; s < SS; s++) {
    float e = act ? E(s, tc) : 0.f;
    float av[NTAG];
    float mx = -3.0e30f;
#pragma unroll
    for (int i = 0; i < NTAG; i++) {
      av[i] = __shfl(alpha, i, 64) + trc[i];
      mx = fmaxf(mx, av[i]);
    }
    float sum = 0.f;
#pragma unroll
    for (int i = 0; i < NTAG; i++) sum += __expf(av[i] - mx);
    float nxt = mx + __logf(sum) + e;
    if (act && mask[b * SS + s] > 0) alpha = nxt;
  }
  float fv = act ? (alpha + end_tr[tc]) : -3.0e30f;
  float q[NTAG];
  float mx2 = -3.0e30f;
#pragma unroll
  for (int i = 0; i < NTAG; i++) {
    q[i] = __shfl(fv, i, 64);
    mx2 = fmaxf(mx2, q[i]);
  }
  float s2 = 0.f;
#pragma unroll
  for (int i = 0; i < NTAG; i++) s2 += __expf(q[i] - mx2);
  float den = mx2 + __logf(s2);

  if (lane == 0) {
    int last = msum - 1;
    int tg0 = target[b * SS + 0];
    int tgl = target[b * SS + last];
    float num = start_tr[tg0] + E(0, tg0) + numpart + end_tr[tgl];
    llh[b] = num - den;
  }
}

__global__ __launch_bounds__(256) void fin_kernel(
    const float* __restrict__ llh, const int* __restrict__ mask,
    float* __restrict__ out)
{
  __shared__ float sf[256];
  __shared__ int   si[256];
  const int t = threadIdx.x;
  float a = (t < BB) ? llh[t] : 0.f;
  int m = 0;
  for (int i = t; i < BB * SS; i += 256) m += mask[i];
  sf[t] = a; si[t] = m;
  __syncthreads();
  for (int o = 128; o > 0; o >>= 1) {
    if (t < o) { sf[t] += sf[t + o]; si[t] += si[t + o]; }
    __syncthreads();
  }
  if (t == 0) out[0] = -(sf[0] / (float)si[0]);
}

// ---------------------------------------------------------------------------
extern "C" void kernel_launch(void* const* d_in, const int* in_sizes, int n_in,
                              void* d_out, int out_size, void* d_ws, size_t ws_size,
                              hipStream_t stream)
{
  const float* x     = (const float*)d_in[0];
  const int*   mask  = (const int*)d_in[1];
  const int*   targ  = (const int*)d_in[2];
  const float* wih_f = (const float*)d_in[3];
  const float* whh_f = (const float*)d_in[4];
  const float* b_f   = (const float*)d_in[5];
  const float* wih_b = (const float*)d_in[6];
  const float* whh_b = (const float*)d_in[7];
  const float* b_b   = (const float*)d_in[8];
  const float* w_out = (const float*)d_in[9];
  const float* b_out = (const float*)d_in[10];
  const float* st    = (const float*)d_in[11];
  const float* et    = (const float*)d_in[12];
  const float* tr    = (const float*)d_in[13];
  float* out = (float*)d_out;

  const size_t nxb   = (size_t)BB * SS * EMBD;       // x bf16 elements
  const size_t nwb   = (size_t)G4 * EMBD;            // w_ih bf16 elements (per dir)
  const size_t ctl_i = sizeof(RecCtl) / 4;
  const size_t fixed_f = (size_t)2 * SS * BB * NTAG + 64 + (size_t)2 * HIDN * BB
                       + ctl_i + nxb / 2 + nwb;
  int chunk = 1;
  for (int c = SS; c >= 1; c >>= 1) {
    size_t need = fixed_f * 4 + (size_t)c * 2 * G4 * BB * 4
                + (size_t)2 * (c + 1) * BB * HIDN * 2;
    if (need <= ws_size) { chunk = c; break; }
  }

  float* fp = (float*)d_ws;
  float* emis_f = fp; fp += (size_t)SS * BB * NTAG;
  float* emis_b = fp; fp += (size_t)SS * BB * NTAG;
  float* llh    = fp; fp += 64;
  float* cT     = fp; fp += (size_t)2 * HIDN * BB;
  RecCtl* ctl   = (RecCtl*)fp; fp += ctl_i;
  __bf16* xb16  = (__bf16*)fp; fp += nxb / 2;
  __bf16* wfb16 = (__bf16*)fp; fp += nwb / 2;
  __bf16* wbb16 = (__bf16*)fp; fp += nwb / 2;
  float* xp     = fp; fp += (size_t)chunk * 2 * G4 * BB;
  __bf16* hh    = (__bf16*)fp;

  // one-time converts (idempotent per launch; inputs restored each replay)
  {
    int n8 = (int)(nxb / 8);
    cvt_kernel<<<dim3((n8 + 255) / 256), 256, 0, stream>>>(x, xb16, n8);
    int w8 = (int)(nwb / 8);
    cvt_kernel<<<dim3((w8 + 255) / 256), 256, 0, stream>>>(wih_f, wfb16, w8);
    cvt_kernel<<<dim3((w8 + 255) / 256), 256, 0, stream>>>(wih_b, wbb16, w8);
  }

  const size_t slotsz = (size_t)BB * HIDN;
  hipMemsetAsync(cT, 0, (size_t)2 * HIDN * BB * sizeof(float), stream);
  hipMemsetAsync(hh, 0, slotsz * sizeof(__bf16), stream);
  hipMemsetAsync(hh + (size_t)(chunk + 1) * slotsz, 0, slotsz * sizeof(__bf16), stream);

  const int nch = SS / chunk;
  for (int c = 0; c < nch; c++) {
    const int t0 = c * chunk;
    hipMemsetAsync(ctl, 0, sizeof(RecCtl), stream);
    proj_kernel<<<dim3(16, chunk, 2), 256, 0, stream>>>(
        xb16, wfb16, wbb16, b_f, b_b, xp, t0, chunk);
    RecParams rp{xp, whh_f, whh_b, hh, cT, ctl, chunk};
    void* ka[] = {&rp};
    hipLaunchCooperativeKernel(rec_kernel, dim3(32), dim3(512), ka, 0, stream);
    emis_kernel<<<dim3(chunk, 2), 256, 0, stream>>>(
        hh, w_out, emis_f, emis_b, t0, chunk);
  }
  crf_kernel<<<dim3(64), 64, 0, stream>>>(emis_f, emis_b, b_out, st, et, tr, mask, targ, llh);
  fin_kernel<<<dim3(1), 256, 0, stream>>>(llh, mask, out);
}

// Round 6
// 4814.266 us; speedup vs baseline: 1.9526x; 1.9526x over previous
//
#include <hip/hip_runtime.h>
#include <cstdint>
#include <cstddef>

#define SS   512
#define BB   64
#define EMBD 768
#define HIDN 512
#define G4   2048
#define NTAG 9

typedef __attribute__((ext_vector_type(8))) __bf16 bf16x8;
typedef __attribute__((ext_vector_type(4))) float  f32x4;
typedef unsigned long long u64;

union HCast { f32x4 f; bf16x8 h; };
union UCast { f32x4 f; unsigned u[4]; };

// ---- device-scope (MALL coherence-point) bypass ops: sc0 sc1 ---------------
// (exact ops proven in R0/R2 across hundreds of replays)
__device__ inline void load_h16_mall(const void* base, f32x4* f) {
  asm volatile(
    "global_load_dwordx4 %0, %16, off sc0 sc1\n\t"
    "global_load_dwordx4 %1, %16, off offset:64 sc0 sc1\n\t"
    "global_load_dwordx4 %2, %16, off offset:128 sc0 sc1\n\t"
    "global_load_dwordx4 %3, %16, off offset:192 sc0 sc1\n\t"
    "global_load_dwordx4 %4, %16, off offset:256 sc0 sc1\n\t"
    "global_load_dwordx4 %5, %16, off offset:320 sc0 sc1\n\t"
    "global_load_dwordx4 %6, %16, off offset:384 sc0 sc1\n\t"
    "global_load_dwordx4 %7, %16, off offset:448 sc0 sc1\n\t"
    "global_load_dwordx4 %8, %16, off offset:512 sc0 sc1\n\t"
    "global_load_dwordx4 %9, %16, off offset:576 sc0 sc1\n\t"
    "global_load_dwordx4 %10, %16, off offset:640 sc0 sc1\n\t"
    "global_load_dwordx4 %11, %16, off offset:704 sc0 sc1\n\t"
    "global_load_dwordx4 %12, %16, off offset:768 sc0 sc1\n\t"
    "global_load_dwordx4 %13, %16, off offset:832 sc0 sc1\n\t"
    "global_load_dwordx4 %14, %16, off offset:896 sc0 sc1\n\t"
    "global_load_dwordx4 %15, %16, off offset:960 sc0 sc1\n\t"
    "s_waitcnt vmcnt(0)"
    : "=&v"(f[0]), "=&v"(f[1]), "=&v"(f[2]), "=&v"(f[3]),
      "=&v"(f[4]), "=&v"(f[5]), "=&v"(f[6]), "=&v"(f[7]),
      "=&v"(f[8]), "=&v"(f[9]), "=&v"(f[10]), "=&v"(f[11]),
      "=&v"(f[12]), "=&v"(f[13]), "=&v"(f[14]), "=&v"(f[15])
    : "v"(base)
    : "memory");
}
__device__ inline void store_h8_mall(void* p, u64 v) {
  asm volatile("global_store_dwordx2 %0, %1, off sc0 sc1" :: "v"(p), "v"(v) : "memory");
}
__device__ inline void store_i32_bypass(int* p, int v) {
  asm volatile("global_store_dword %0, %1, off sc0 sc1" :: "v"(p), "v"(v) : "memory");
}
__device__ inline int load_i32_bypass(const int* p) {
  int v;
  asm volatile("global_load_dword %0, %1, off sc0 sc1\n\ts_waitcnt vmcnt(0)"
               : "=v"(v) : "v"(p) : "memory");
  return v;
}

__device__ inline bool frag_clean(const f32x4* araw) {
  unsigned mx = 0u;
#pragma unroll
  for (int kk = 0; kk < 16; kk++) {
    UCast q; q.f = araw[kk];
    unsigned a01 = q.u[0] > q.u[1] ? q.u[0] : q.u[1];
    unsigned a23 = q.u[2] > q.u[3] ? q.u[2] : q.u[3];
    unsigned am  = a01 > a23 ? a01 : a23;
    mx = mx > am ? mx : am;
  }
  return __all(mx != 0xFFFFFFFFu);
}

// ---------------------------------------------------------------------------
// fp32 -> bf16 converter
// ---------------------------------------------------------------------------
__global__ __launch_bounds__(256) void cvt_kernel(
    const float* __restrict__ src, __bf16* __restrict__ dst, int n8)
{
  int i = blockIdx.x * 256 + threadIdx.x;
  if (i >= n8) return;
  f32x4 a = *reinterpret_cast<const f32x4*>(src + 8 * (size_t)i);
  f32x4 b = *reinterpret_cast<const f32x4*>(src + 8 * (size_t)i + 4);
  bf16x8 o;
  o[0]=(__bf16)a[0]; o[1]=(__bf16)a[1]; o[2]=(__bf16)a[2]; o[3]=(__bf16)a[3];
  o[4]=(__bf16)b[0]; o[5]=(__bf16)b[1]; o[6]=(__bf16)b[2]; o[7]=(__bf16)b[3];
  *reinterpret_cast<bf16x8*>(dst + 8 * (size_t)i) = o;
}

// ---------------------------------------------------------------------------
// Input projection, bf16 MFMA (unchanged, verified).
// ---------------------------------------------------------------------------
__global__ __launch_bounds__(256, 2) void proj_kernel(
    const __bf16* __restrict__ xb, const __bf16* __restrict__ wfb,
    const __bf16* __restrict__ wbb, const float* __restrict__ bias_f,
    const float* __restrict__ bias_b, float* __restrict__ xp,
    int t0, int chunk)
{
  const int nb = blockIdx.x;
  const int tt = blockIdx.y;
  const int d  = blockIdx.z;
  const int s  = d ? (SS - 1 - (t0 + tt)) : (t0 + tt);
  const __bf16* __restrict__ wih = d ? wbb : wfb;
  const float*  __restrict__ bias = d ? bias_b : bias_f;

  const int t = threadIdx.x, wv = t >> 6, l = t & 63;
  const int quad = l >> 4, col = l & 15;

  const __bf16* brow[8];
  float bj[8];
  const int pbase = 128 * nb;
#pragma unroll
  for (int j = 0; j < 8; j++) {
    int p    = pbase + 16 * j + col;
    int gate = p & 3;
    int hc   = 16 * (p >> 6) + 4 * ((p >> 2) & 3) + ((p >> 4) & 3);
    int g    = gate * HIDN + hc;
    brow[j]  = wih + (size_t)g * EMBD + 8 * quad;
    bj[j]    = bias[g];
  }
  const __bf16* arow = xb + ((size_t)(16 * wv + col) * SS + s) * EMBD + 8 * quad;

  f32x4 acc[8];
#pragma unroll
  for (int j = 0; j < 8; j++) acc[j] = f32x4{0.f, 0.f, 0.f, 0.f};

  for (int kk = 0; kk < 24; kk++) {
    bf16x8 a = *reinterpret_cast<const bf16x8*>(arow + 32 * kk);
#pragma unroll
    for (int j = 0; j < 8; j++) {
      bf16x8 b = *reinterpret_cast<const bf16x8*>(brow[j] + 32 * kk);
      acc[j] = __builtin_amdgcn_mfma_f32_16x16x32_bf16(a, b, acc[j], 0, 0, 0);
    }
  }
  float* xpd = xp + (size_t)(d * chunk + tt) * (size_t)G4 * BB + 16 * wv + 4 * quad;
#pragma unroll
  for (int j = 0; j < 8; j++) {
    int p = pbase + 16 * j + col;
    f32x4 v = acc[j];
    v[0] += bj[j]; v[1] += bj[j]; v[2] += bj[j]; v[3] += bj[j];
    *reinterpret_cast<f32x4*>(xpd + (size_t)p * BB) = v;
  }
}

// ---------------------------------------------------------------------------
// Recurrence: 64 WGs x 256 thr (R0/R2 structure). Hybrid sync per step:
//   FAST PATH: speculative bulk h-load + bf16-NaN sentinel check (R2-proven
//     dataflow; 0xFFFF impossible for real h since |h|<=1). If clean: one
//     round trip, no barriers, no flag wait in the consumer path.
//   SLOW PATH: on sentinel, poll 4B per-WG progress flags (R0-proven
//     ordering: producers drain h stores, barrier, then publish flag), then
//     reload + re-validate. Tiny poll payload -> no MALL congestion storms.
// ---------------------------------------------------------------------------
struct RecCtl {
  int prog[2][64];   // per-dir step flags (slots 0..31 used per dir)
  int start[64];     // startup sentinel-fill barrier
  int fin[64];       // chunk==1 tail barrier
  int pad[64];
};

struct RecParams {
  const float* xp;       // [d][chunk][2048 packed][64] fp32
  const float* whh_f;    // [2048][512] fp32
  const float* whh_b;
  __bf16* hh;            // [d][chunk+1][64][512] bf16
  float*  cT;            // [d][512][64] fp32
  RecCtl* ctl;
  int     chunk;
};

__global__ __launch_bounds__(256, 1) void rec_kernel(RecParams p)
{
  const int wg   = blockIdx.x;
  const int d    = wg >> 5;
  const int sl   = wg & 31;
  const int t    = threadIdx.x;
  const int wv   = t >> 6;
  const int l    = t & 63;
  const int quad = l >> 4;
  const int col  = l & 15;
  const int hcl  = col >> 2;
  const int gate = col & 3;
  const int j4   = col & 3;

  const size_t slotsz = (size_t)BB * HIDN;

  // ---- prologue: sentinel-fill slots 1..chunk (both dirs), bypass stores ---
  {
    const size_t qper = (size_t)p.chunk * slotsz / 4;   // 8B qwords per dir
    const size_t totq = 2 * qper;
    const size_t gtid = (size_t)wg * 256 + t;
    for (size_t q = gtid; q < totq; q += (size_t)64 * 256) {
      const size_t dd  = q / qper;
      const size_t off = q - dd * qper;
      store_h8_mall((char*)p.hh + (dd * (p.chunk + 1) + 1) * slotsz * 2 + off * 8,
                    0xFFFFFFFFFFFFFFFFull);
    }
    __builtin_amdgcn_s_waitcnt(0);
    __syncthreads();
    if (t == 0) store_i32_bypass(&p.ctl->start[wg], 1);
    if (wv == 0) {
      const int* slot = &p.ctl->start[l];
      while (true) {
        int v = load_i32_bypass(slot);
        if (__ballot(v != 0) == ~0ull) break;
        __builtin_amdgcn_s_sleep(2);
      }
    }
    __syncthreads();
  }

  const float* __restrict__ whh = d ? p.whh_b : p.whh_f;

  bf16x8 bfrag[4][16];
#pragma unroll
  for (int j = 0; j < 4; j++) {
    const int hcb = 16 * sl + 4 * hcl + j;
    const float* wr = whh + (size_t)(gate * HIDN + hcb) * HIDN + 8 * quad;
#pragma unroll
    for (int kk = 0; kk < 16; kk++) {
      f32x4 w0 = *reinterpret_cast<const f32x4*>(wr + 32 * kk);
      f32x4 w1 = *reinterpret_cast<const f32x4*>(wr + 32 * kk + 4);
      bf16x8 v;
      v[0] = (__bf16)w0[0]; v[1] = (__bf16)w0[1]; v[2] = (__bf16)w0[2]; v[3] = (__bf16)w0[3];
      v[4] = (__bf16)w1[0]; v[5] = (__bf16)w1[1]; v[6] = (__bf16)w1[2]; v[7] = (__bf16)w1[3];
      bfrag[j][kk] = v;
    }
  }

  const int bA = 16 * wv + col;
  const int bC = 16 * wv + 4 * quad + gate;
  const int hcs = 16 * sl + 4 * hcl;
  __bf16* hhd = p.hh + (size_t)d * (p.chunk + 1) * slotsz;
  const float* xpd = p.xp + (size_t)d * p.chunk * ((size_t)G4 * BB);

  float c[4];
#pragma unroll
  for (int j = 0; j < 4; j++)
    c[j] = p.cT[((size_t)d * HIDN + hcs + j) * BB + bC];

  f32x4 xpn[4];
#pragma unroll
  for (int j = 0; j < 4; j++)
    xpn[j] = *reinterpret_cast<const f32x4*>(
        xpd + (size_t)(64 * sl + 16 * j + col) * BB + 16 * wv + 4 * quad);

  int* prog = &p.ctl->prog[d][0];
  const int* myfl = prog + (l & 31);

  u64 hword = 0;
  for (int tt = 0; tt < p.chunk; tt++) {
    const char* hbase = (const char*)hhd + (size_t)tt * slotsz * 2
                      + (size_t)bA * (HIDN * 2) + quad * 16;
    f32x4 araw[16];
    // --- speculative fast path: one RT, validated by sentinel ---
    load_h16_mall(hbase, araw);
    if (!frag_clean(araw)) {
      // --- slow path: cheap 4B flag wait (R0 ordering), then reload ---
      while (true) {
        int v = load_i32_bypass(myfl);
        if (__ballot(v >= tt) == ~0ull) break;
        __builtin_amdgcn_s_sleep(2);
      }
      for (;;) {
        load_h16_mall(hbase, araw);
        if (frag_clean(araw)) break;
        __builtin_amdgcn_s_sleep(2);
      }
    }
    bf16x8 afrag[16];
#pragma unroll
    for (int kk = 0; kk < 16; kk++) { HCast hc_; hc_.f = araw[kk]; afrag[kk] = hc_.h; }

    f32x4 acc[4][2];
#pragma unroll
    for (int j = 0; j < 4; j++) {
      acc[j][0] = xpn[j];
      acc[j][1] = f32x4{0.f, 0.f, 0.f, 0.f};
    }
#pragma unroll
    for (int kk = 0; kk < 16; kk += 2) {
#pragma unroll
      for (int j = 0; j < 4; j++) {
        acc[j][0] = __builtin_amdgcn_mfma_f32_16x16x32_bf16(afrag[kk],     bfrag[j][kk],     acc[j][0], 0, 0, 0);
        acc[j][1] = __builtin_amdgcn_mfma_f32_16x16x32_bf16(afrag[kk + 1], bfrag[j][kk + 1], acc[j][1], 0, 0, 0);
      }
    }

    hword = 0;
#pragma unroll
    for (int j = 0; j < 4; j++) {
      float v0 = acc[j][0][0] + acc[j][1][0];
      float v1 = acc[j][0][1] + acc[j][1][1];
      float v2 = acc[j][0][2] + acc[j][1][2];
      float v3 = acc[j][0][3] + acc[j][1][3];
      {
        float t0 = __shfl_xor(v1, 1); float t1 = __shfl_xor(v0, 1);
        float t2 = __shfl_xor(v3, 1); float t3 = __shfl_xor(v2, 1);
        if (j4 & 1) { v0 = t0; v2 = t2; } else { v1 = t1; v3 = t3; }
        float u0 = __shfl_xor(v2, 2); float u1 = __shfl_xor(v3, 2);
        float u2 = __shfl_xor(v0, 2); float u3 = __shfl_xor(v1, 2);
        if (j4 & 2) { v0 = u0; v1 = u1; } else { v2 = u2; v3 = u3; }
      }
      float ig = 1.f / (1.f + __expf(-v0));
      float fg = 1.f / (1.f + __expf(-v1));
      float gg = 1.f - 2.f / (__expf(2.f * v2) + 1.f);
      float og = 1.f / (1.f + __expf(-v3));
      c[j] = fg * c[j] + ig * gg;
      float hn = og * (1.f - 2.f / (__expf(2.f * c[j]) + 1.f));
      union { __bf16 b; unsigned short u; } cv; cv.b = (__bf16)hn;
      hword |= (u64)cv.u << (16 * j);
    }
    store_h8_mall((char*)hhd + (size_t)(tt + 1) * slotsz * 2
                  + (size_t)bC * (HIDN * 2) + (size_t)hcs * 2, hword);

    if (tt + 1 < p.chunk) {
#pragma unroll
      for (int j = 0; j < 4; j++)
        xpn[j] = *reinterpret_cast<const f32x4*>(
            xpd + (size_t)(tt + 1) * ((size_t)G4 * BB)
            + (size_t)(64 * sl + 16 * j + col) * BB + 16 * wv + 4 * quad);
    }

    // --- publish progress (R0-proven ordering): drain h store across the
    //     whole WG, then one flag store. No polling in the common path.
    __builtin_amdgcn_s_waitcnt(0);
    __syncthreads();
    if (t == 0) store_i32_bypass(prog + sl, tt + 1);
  }

  // chunk==1 safety: carry store to slot 0 could race a WG still at tt=0.
  if (p.chunk == 1) {
    __builtin_amdgcn_s_waitcnt(0);
    __syncthreads();
    if (t == 0) store_i32_bypass(&p.ctl->fin[wg], 1);
    if (wv == 0) {
      const int* slot = &p.ctl->fin[l];
      while (true) {
        int v = load_i32_bypass(slot);
        if (__ballot(v != 0) == ~0ull) break;
        __builtin_amdgcn_s_sleep(2);
      }
    }
    __syncthreads();
  }

  store_h8_mall((char*)hhd + (size_t)bC * (HIDN * 2) + (size_t)hcs * 2, hword);
#pragma unroll
  for (int j = 0; j < 4; j++)
    p.cT[((size_t)d * HIDN + hcs + j) * BB + bC] = c[j];
  __builtin_amdgcn_s_waitcnt(0);
}

// ---------------------------------------------------------------------------
__global__ __launch_bounds__(256) void emis_kernel(
    const __bf16* __restrict__ hh, const float* __restrict__ w_out,
    float* __restrict__ emis_f, float* __restrict__ emis_b,
    int t0, int chunk)
{
  const int tt = blockIdx.x;
  const int d  = blockIdx.y;
  const int t  = threadIdx.x;
  const int b  = t & 63;
  const int grp = t >> 6;

  const __bf16* hp = hh + ((size_t)d * (chunk + 1) + tt + 1) * ((size_t)BB * HIDN)
                   + (size_t)b * HIDN;
  const float* w0 = w_out + (size_t)grp * (2 * HIDN) + d * HIDN;
  const float* w1 = w_out + (size_t)(grp + 4) * (2 * HIDN) + d * HIDN;
  const float* w2 = w_out + (size_t)8 * (2 * HIDN) + d * HIDN;

  float a0 = 0.f, a1 = 0.f, a2 = 0.f;
  for (int k = 0; k < HIDN; k += 8) {
    bf16x8 hv8 = *reinterpret_cast<const bf16x8*>(hp + k);
#pragma unroll
    for (int j = 0; j < 8; j++) {
      float hv = (float)hv8[j];
      a0 += hv * w0[k + j];
      a1 += hv * w1[k + j];
      a2 += hv * w2[k + j];
    }
  }
  const int sidx = (d == 0) ? (t0 + tt) : (SS - 1 - (t0 + tt));
  float* dst = d ? emis_b : emis_f;
  dst[((size_t)sidx * BB + b) * NTAG + grp]     = a0;
  dst[((size_t)sidx * BB + b) * NTAG + grp + 4] = a1;
  if (grp == 0) dst[((size_t)sidx * BB + b) * NTAG + 8] = a2;
}

// ---------------------------------------------------------------------------
__global__ __launch_bounds__(64) void crf_kernel(
    const float* __restrict__ emis_f, const float* __restrict__ emis_b,
    const float* __restrict__ b_out, const float* __restrict__ start_tr,
    const float* __restrict__ end_tr, const float* __restrict__ trans,
    const int* __restrict__ mask, const int* __restrict__ target,
    float* __restrict__ llh)
{
  const int b    = blockIdx.x;
  const int lane = threadIdx.x;

  auto E = [&](int s, int tg) -> float {
    size_t o = ((size_t)s * BB + b) * NTAG + tg;
    return emis_f[o] + emis_b[o] + b_out[tg];
  };

  float numpart = 0.f;
  int msum = 0;
  for (int s = lane; s < SS; s += 64) {
    int m = mask[b * SS + s];
    msum += m;
    if (s >= 1 && m > 0) {
      int tp = target[b * SS + s - 1];
      int tc = target[b * SS + s];
      numpart += trans[tp * NTAG + tc] + E(s, tc);
    }
  }
#pragma unroll
  for (int off = 32; off > 0; off >>= 1) {
    numpart += __shfl_down(numpart, off, 64);
    msum    += __shfl_down(msum, off, 64);
  }

  const int tc = lane;
  const bool act = (tc < NTAG);
  float trc[NTAG] = {0.f};
  float alpha = 0.f;
  if (act) {
#pragma unroll
    for (int i = 0; i < NTAG; i++) trc[i] = trans[i * NTAG + tc];
    alpha = start_tr[tc] + E(0, tc);
  }
  for (int s = 1; s < SS; s++) {
    float e = act ? E(s, tc) : 0.f;
    float av[NTAG];
    float mx = -3.0e30f;
#pragma unroll
    for (int i = 0; i < NTAG; i++) {
      av[i] = __shfl(alpha, i, 64) + trc[i];
      mx = fmaxf(mx, av[i]);
    }
    float sum = 0.f;
#pragma unroll
    for (int i = 0; i < NTAG; i++) sum += __expf(av[i] - mx);
    float nxt = mx + __logf(sum) + e;
    if (act && mask[b * SS + s] > 0) alpha = nxt;
  }
  float fv = act ? (alpha + end_tr[tc]) : -3.0e30f;
  float q[NTAG];
  float mx2 = -3.0e30f;
#pragma unroll
  for (int i = 0; i < NTAG; i++) {
    q[i] = __shfl(fv, i, 64);
    mx2 = fmaxf(mx2, q[i]);
  }
  float s2 = 0.f;
#pragma unroll
  for (int i = 0; i < NTAG; i++) s2 += __expf(q[i] - mx2);
  float den = mx2 + __logf(s2);

  if (lane == 0) {
    int last = msum - 1;
    int tg0 = target[b * SS + 0];
    int tgl = target[b * SS + last];
    float num = start_tr[tg0] + E(0, tg0) + numpart + end_tr[tgl];
    llh[b] = num - den;
  }
}

__global__ __launch_bounds__(256) void fin_kernel(
    const float* __restrict__ llh, const int* __restrict__ mask,
    float* __restrict__ out)
{
  __shared__ float sf[256];
  __shared__ int   si[256];
  const int t = threadIdx.x;
  float a = (t < BB) ? llh[t] : 0.f;
  int m = 0;
  for (int i = t; i < BB * SS; i += 256) m += mask[i];
  sf[t] = a; si[t] = m;
  __syncthreads();
  for (int o = 128; o > 0; o >>= 1) {
    if (t < o) { sf[t] += sf[t + o]; si[t] += si[t + o]; }
    __syncthreads();
  }
  if (t == 0) out[0] = -(sf[0] / (float)si[0]);
}

// ---------------------------------------------------------------------------
extern "C" void kernel_launch(void* const* d_in, const int* in_sizes, int n_in,
                              void* d_out, int out_size, void* d_ws, size_t ws_size,
                              hipStream_t stream)
{
  const float* x     = (const float*)d_in[0];
  const int*   mask  = (const int*)d_in[1];
  const int*   targ  = (const int*)d_in[2];
  const float* wih_f = (const float*)d_in[3];
  const float* whh_f = (const float*)d_in[4];
  const float* b_f   = (const float*)d_in[5];
  const float* wih_b = (const float*)d_in[6];
  const float* whh_b = (const float*)d_in[7];
  const float* b_b   = (const float*)d_in[8];
  const float* w_out = (const float*)d_in[9];
  const float* b_out = (const float*)d_in[10];
  const float* st    = (const float*)d_in[11];
  const float* et    = (const float*)d_in[12];
  const float* tr    = (const float*)d_in[13];
  float* out = (float*)d_out;

  const size_t nxb   = (size_t)BB * SS * EMBD;       // x bf16 elements
  const size_t nwb   = (size_t)G4 * EMBD;            // w_ih bf16 elements (per dir)
  const size_t ctl_i = sizeof(RecCtl) / 4;
  const size_t fixed_f = (size_t)2 * SS * BB * NTAG + 64 + (size_t)2 * HIDN * BB
                       + ctl_i + nxb / 2 + nwb;
  int chunk = 1;
  for (int c = SS; c >= 1; c >>= 1) {
    size_t need = fixed_f * 4 + (size_t)c * 2 * G4 * BB * 4
                + (size_t)2 * (c + 1) * BB * HIDN * 2;
    if (need <= ws_size) { chunk = c; break; }
  }

  float* fp = (float*)d_ws;
  float* emis_f = fp; fp += (size_t)SS * BB * NTAG;
  float* emis_b = fp; fp += (size_t)SS * BB * NTAG;
  float* llh    = fp; fp += 64;
  float* cT     = fp; fp += (size_t)2 * HIDN * BB;
  RecCtl* ctl   = (RecCtl*)fp; fp += ctl_i;
  __bf16* xb16  = (__bf16*)fp; fp += nxb / 2;
  __bf16* wfb16 = (__bf16*)fp; fp += nwb / 2;
  __bf16* wbb16 = (__bf16*)fp; fp += nwb / 2;
  float* xp     = fp; fp += (size_t)chunk * 2 * G4 * BB;
  __bf16* hh    = (__bf16*)fp;

  // one-time converts (idempotent per launch; inputs restored each replay)
  {
    int n8 = (int)(nxb / 8);
    cvt_kernel<<<dim3((n8 + 255) / 256), 256, 0, stream>>>(x, xb16, n8);
    int w8 = (int)(nwb / 8);
    cvt_kernel<<<dim3((w8 + 255) / 256), 256, 0, stream>>>(wih_f, wfb16, w8);
    cvt_kernel<<<dim3((w8 + 255) / 256), 256, 0, stream>>>(wih_b, wbb16, w8);
  }

  const size_t slotsz = (size_t)BB * HIDN;
  hipMemsetAsync(cT, 0, (size_t)2 * HIDN * BB * sizeof(float), stream);
  hipMemsetAsync(hh, 0, slotsz * sizeof(__bf16), stream);
  hipMemsetAsync(hh + (size_t)(chunk + 1) * slotsz, 0, slotsz * sizeof(__bf16), stream);

  const int nch = SS / chunk;
  for (int c = 0; c < nch; c++) {
    const int t0 = c * chunk;
    hipMemsetAsync(ctl, 0, sizeof(RecCtl), stream);
    proj_kernel<<<dim3(16, chunk, 2), 256, 0, stream>>>(
        xb16, wfb16, wbb16, b_f, b_b, xp, t0, chunk);
    RecParams rp{xp, whh_f, whh_b, hh, cT, ctl, chunk};
    void* ka[] = {&rp};
    hipLaunchCooperativeKernel(rec_kernel, dim3(64), dim3(256), ka, 0, stream);
    emis_kernel<<<dim3(chunk, 2), 256, 0, stream>>>(
        hh, w_out, emis_f, emis_b, t0, chunk);
  }
  crf_kernel<<<dim3(64), 64, 0, stream>>>(emis_f, emis_b, b_out, st, et, tr, mask, targ, llh);
  fin_kernel<<<dim3(1), 256, 0, stream>>>(llh, mask, out);
}